// Round 3
// baseline (394.270 us; speedup 1.0000x reference)
//
#include <hip/hip_runtime.h>
#include <hip/hip_fp16.h>
#include <cstdint>

// Problem constants (fixed by the reference)
#define NROWS 65536
#define DIM   512    // D
#define KDIM  256    // K
#define ODIM  512    // O
#define DEG   8
#define ZN    (NROWS * DIM)        // 33554432 z elements
#define TN    (DEG * KDIM * DIM)   // 1048576 T elements
#define CWN   (ODIM * KDIM)        // 131072 C_w elements

typedef _Float16 f16x8 __attribute__((ext_vector_type(8)));
typedef float    f32x4 __attribute__((ext_vector_type(4)));

// ---- helpers -------------------------------------------------------------

// async 16B global->LDS (global_load_lds_dwordx4). LDS dest is wave-uniform
// base + lane*16 by HW rule; all our slot mappings honor that.
__device__ __forceinline__ void gld_lds16(const void* g, void* l) {
  __builtin_amdgcn_global_load_lds(
      (const __attribute__((address_space(1))) unsigned int*)g,
      (__attribute__((address_space(3))) unsigned int*)l, 16, 0, 0);
}

__device__ __forceinline__ unsigned pack2h(float a, float b) {
  union { _Float16 h[2]; unsigned u; } x;
  x.h[0] = (_Float16)a; x.h[1] = (_Float16)b;
  return x.u;
}

// Swizzled byte offset in a tile of 64-half rows (128B = 8 x 16B chunks).
// chunk c of row r lives at slot (c+r)&7 -> conflict-free ds_read_b128.
__device__ __forceinline__ int swz(int row, int chunk) {
  return (row << 7) | (((chunk + row) & 7) << 4);
}

// ---- kernel 0: fp32->fp16 conversions (z, T with a_n folded, C_w) --------
// 8 elems/thread: 2x float4 in, 1x uint4 (16B) out — copy-shaped (m13).

__global__ void k_convert(const float* __restrict__ z,
                          const float* __restrict__ T,
                          const float* __restrict__ Cw,
                          _Float16* __restrict__ z16,
                          _Float16* __restrict__ Tb,
                          _Float16* __restrict__ Cwb) {
  long e = ((long)blockIdx.x * 256 + threadIdx.x) * 8;
  const float* src;
  _Float16* dst;
  float s = 1.0f;
  if (e < ZN) {
    src = z + e; dst = z16 + e;
  } else {
    long o = e - ZN;
    if (o < TN) {
      int n = (int)(o >> 17);  // / (KDIM*DIM); Tb[n] holds degree n+1
      s = (n == 0) ? 1.0f : (float)(2 * n + 1) / (float)(n + 1);
      src = T + o; dst = Tb + o;
    } else {
      long c = o - TN;
      if (c >= CWN) return;
      src = Cw + c; dst = Cwb + c;
    }
  }
  float4 v0 = *(const float4*)src;
  float4 v1 = *(const float4*)(src + 4);
  uint4 p;
  p.x = pack2h(v0.x * s, v0.y * s); p.y = pack2h(v0.z * s, v0.w * s);
  p.z = pack2h(v1.x * s, v1.y * s); p.w = pack2h(v1.z * s, v1.w * s);
  *(uint4*)dst = p;
}

// ---- kernel 1: fused GEMM [Nx512]x[512x(16x8deg)] + degree recurrence ----
// A path: reg-staged from z16 at PREFETCH DISTANCE 2 (A(it+2) issued during
// iter it), ds_write_b128 into swizzled As. B path: gld_lds, dbuf, dist 1.
// Per-wave vmcnt ledger at the wait in iter it (issue order pinned by
// sched_barrier groups; B(it+1) issued before A(it+2) each iter):
//   outstanding = A(it):4 (issued it-2) + B(it):4 (it-1) + A(it+1):4 (it-1)
//   -> vmcnt(4) drains A(it),B(it); both >=1 full iteration old.
// Nothing is issued-then-immediately-drained (round-2's exposed A stall).

__launch_bounds__(256, 3)
__global__ void k_poly(const _Float16* __restrict__ z16,
                       const float* __restrict__ T0,
                       const _Float16* __restrict__ Tb,
                       _Float16* __restrict__ u8) {
  __shared__ __align__(16) uint16_t As[128 * 64];      // 16 KB z tile
  __shared__ __align__(16) uint16_t Bs[2][128 * 64];   // 2 x 16 KB Tb tile

  const int tid = threadIdx.x;
  const int wave = tid >> 6, lane = tid & 63;

  // super-tile: 16 row-tiles x 16 k-groups -> z16 slice (2MB) + Tb (2MB) ~ L2
  const int id = blockIdx.x;
  const int super = id >> 8, rem = id & 255;
  const int kg = rem >> 4;                    // 0..15 (16 u-cols each)
  const int rt = (super << 4) | (rem & 15);   // 0..511 row tile
  const int r0 = rt << 7;
  const int k0 = kg << 4;

  const int m_l = lane & 15, kq = lane >> 4;
  const int wrow = wave << 5;                 // 32 rows per wave

  f32x4 acc[DEG][2];
#pragma unroll
  for (int n = 0; n < DEG; n++)
#pragma unroll
    for (int a = 0; a < 2; a++)
      acc[n][a] = (f32x4){0.f, 0.f, 0.f, 0.f};

  // Staging slots. lin=j*256+tid, row=lin>>3, c=((lin&7)-row)&7 inverts the
  // swizzle on the global side; LDS dest (lofs) is linear.
  const _Float16* aptr[4];   // z16 source for this thread's 4 A slots
  const _Float16* bptr[4];
  int lofs[4];
#pragma unroll
  for (int j = 0; j < 4; j++) {
    int lin = (j << 8) + tid;
    int row = lin >> 3;
    int c = ((lin & 7) - row) & 7;
    lofs[j] = lin << 4;
    aptr[j] = z16 + (size_t)(r0 + row) * DIM + (c << 3);
    int n = row >> 4, kk = row & 15;
    bptr[j] = Tb + (size_t)((n << 8) + k0 + kk) * DIM + (c << 3);
  }

  // A register staging buffers, parity it&1; all indices static after unroll.
  uint4 aR[2][4];

  // Prologue: issue A(0), B(0), A(1) — in that order (ledger depends on it).
#pragma unroll
  for (int j = 0; j < 4; j++)
    aR[0][j] = *reinterpret_cast<const uint4*>(aptr[j]);
  __builtin_amdgcn_sched_barrier(0);
#pragma unroll
  for (int j = 0; j < 4; j++) gld_lds16(bptr[j], (char*)Bs[0] + lofs[j]);
  __builtin_amdgcn_sched_barrier(0);
#pragma unroll
  for (int j = 0; j < 4; j++)
    aR[1][j] = *reinterpret_cast<const uint4*>(aptr[j] + 64);
  __builtin_amdgcn_sched_barrier(0);

#pragma unroll
  for (int it = 0; it < DIM / 64; it++) {
    const int cur = it & 1;
    __builtin_amdgcn_s_barrier();   // compute(it-1) readers of As/Bs[cur^1] done
    if (it < DIM / 64 - 1)
      asm volatile("s_waitcnt vmcnt(4)" ::: "memory");  // drain A(it),B(it)
    else
      asm volatile("s_waitcnt vmcnt(0)" ::: "memory");
    __builtin_amdgcn_sched_barrier(0);

    // A(it): regs -> swizzled As (ds_write_b128)
#pragma unroll
    for (int j = 0; j < 4; j++)
      *(uint4*)((char*)As + lofs[j]) = aR[cur][j];
    __builtin_amdgcn_sched_barrier(0);

    // issue B(it+1) -> Bs[cur^1] (stays in flight across compute)
    if (it + 1 < DIM / 64) {
#pragma unroll
      for (int j = 0; j < 4; j++)
        gld_lds16(bptr[j] + ((it + 1) << 6), (char*)Bs[cur ^ 1] + lofs[j]);
    }
    __builtin_amdgcn_sched_barrier(0);

    // issue A(it+2) -> aR[cur] (distance 2; in flight for ~2 iterations)
    if (it + 2 < DIM / 64) {
#pragma unroll
      for (int j = 0; j < 4; j++)
        aR[cur][j] = *reinterpret_cast<const uint4*>(aptr[j] + ((it + 2) << 6));
    }
    __builtin_amdgcn_sched_barrier(0);

    asm volatile("s_waitcnt lgkmcnt(0)" ::: "memory");  // As writes visible
    __builtin_amdgcn_sched_barrier(0);
    __builtin_amdgcn_s_barrier();   // all waves' A(it),B(it) staged
    __builtin_amdgcn_sched_barrier(0);

    // compute tile it
#pragma unroll
    for (int ks = 0; ks < 2; ks++) {
      const int chunk = (ks << 2) + kq;
      f16x8 af[2];
#pragma unroll
      for (int mf = 0; mf < 2; mf++)
        af[mf] = *(const f16x8*)((char*)As + swz(wrow + (mf << 4) + m_l, chunk));
#pragma unroll
      for (int n = 0; n < DEG; n++) {
        f16x8 bv = *(const f16x8*)((char*)Bs[cur] + swz((n << 4) + m_l, chunk));
#pragma unroll
        for (int mf = 0; mf < 2; mf++)
          acc[n][mf] = __builtin_amdgcn_mfma_f32_16x16x32_f16(
              af[mf], bv, acc[n][mf], 0, 0, 0);
      }
    }
  }

  // Legendre recurrence per accumulator element, store u8 fp16.
  // C/D layout: col = lane&15, row = (lane>>4)*4 + reg  [m89-verified]
  const float bcoef[7] = {1.f/2.f, 2.f/3.f, 3.f/4.f, 4.f/5.f,
                          5.f/6.f, 6.f/7.f, 7.f/8.f};
  const int col = k0 + m_l;
  const float t0v = T0[col];
#pragma unroll
  for (int mf = 0; mf < 2; mf++) {
    f32x4 up2 = {t0v, t0v, t0v, t0v};
    f32x4 up1 = acc[0][mf];
#pragma unroll
    for (int n = 2; n <= DEG; n++) {
      f32x4 cur = acc[n - 1][mf] * up1 - bcoef[n - 2] * up2;
      up2 = up1; up1 = cur;
    }
    const int rbase = r0 + wrow + (mf << 4) + (kq << 2);
#pragma unroll
    for (int r = 0; r < 4; r++)
      u8[(size_t)(rbase + r) * KDIM + col] = (_Float16)up1[r];
  }
}

// ---- kernel 2: out[N,512] = u8[N,256] @ Cw^T + C_b (fp32 out) ------------
// Block tile 128 rows x 64 out-cols; 4 K-iterations of 64.
// Both As and Bs double-buffered, counted vmcnt(6): ledger at the wait in
// iter it: A(it):4 + B(it):2 (issued it-1) + A(it+1):4 + B(it+1):2 (just
// issued) = 12 -> vmcnt(6) drains A(it),B(it), leaves it+1 in flight.
// XCD swizzle: 8 cg blocks of a row tile share u8 rows -> same XCD L2.

__launch_bounds__(256, 3)
__global__ void k_out(const _Float16* __restrict__ u8,
                      const _Float16* __restrict__ Cwb,
                      const float* __restrict__ Cb,
                      float* __restrict__ out) {
  __shared__ __align__(16) uint16_t As[2][128 * 64];  // 2 x 16 KB u8 tile
  __shared__ __align__(16) uint16_t Bs[2][64 * 64];   // 2 x  8 KB Cw tile

  const int tid = threadIdx.x;
  const int wave = tid >> 6, lane = tid & 63;

  const int id = blockIdx.x;
  const int xcd = id & 7;
  const int s = id >> 3;                     // 0..511
  const int cg = s & 7;                      // 0..7 out-col group (64)
  const int rt = (xcd << 6) | (s >> 3);      // 0..511 row tile
  const int r0 = rt << 7;
  const int c0 = cg << 6;

  const int m_l = lane & 15, kq = lane >> 4;
  const int wrow = wave << 5;

  f32x4 acc[2][4];
#pragma unroll
  for (int a = 0; a < 2; a++)
#pragma unroll
    for (int b = 0; b < 4; b++)
      acc[a][b] = (f32x4){0.f, 0.f, 0.f, 0.f};

  const _Float16* aptr[4];
  const _Float16* bptr[2];
  int lofsA[4], lofsB[2];
#pragma unroll
  for (int j = 0; j < 4; j++) {
    int lin = (j << 8) + tid;
    int row = lin >> 3;
    int c = ((lin & 7) - row) & 7;
    lofsA[j] = lin << 4;
    aptr[j] = u8 + (size_t)(r0 + row) * KDIM + (c << 3);
  }
#pragma unroll
  for (int j = 0; j < 2; j++) {
    int lin = (j << 8) + tid;
    int row = lin >> 3;
    int c = ((lin & 7) - row) & 7;
    lofsB[j] = lin << 4;
    bptr[j] = Cwb + (size_t)(c0 + row) * KDIM + (c << 3);
  }

  // Prologue: issue A(0) then B(0) (order pinned; ledger depends on it).
#pragma unroll
  for (int j = 0; j < 4; j++) gld_lds16(aptr[j], (char*)As[0] + lofsA[j]);
  __builtin_amdgcn_sched_barrier(0);
#pragma unroll
  for (int j = 0; j < 2; j++) gld_lds16(bptr[j], (char*)Bs[0] + lofsB[j]);
  __builtin_amdgcn_sched_barrier(0);

#pragma unroll
  for (int it = 0; it < KDIM / 64; it++) {
    const int cur = it & 1;
    __builtin_amdgcn_s_barrier();   // readers of [cur^1] buffers done
    __builtin_amdgcn_sched_barrier(0);

    if (it + 1 < KDIM / 64) {
#pragma unroll
      for (int j = 0; j < 4; j++)
        gld_lds16(aptr[j] + ((it + 1) << 6), (char*)As[cur ^ 1] + lofsA[j]);
      __builtin_amdgcn_sched_barrier(0);
#pragma unroll
      for (int j = 0; j < 2; j++)
        gld_lds16(bptr[j] + ((it + 1) << 6), (char*)Bs[cur ^ 1] + lofsB[j]);
      __builtin_amdgcn_sched_barrier(0);
      asm volatile("s_waitcnt vmcnt(6)" ::: "memory");  // drain A(it),B(it)
    } else {
      asm volatile("s_waitcnt vmcnt(0)" ::: "memory");
    }
    __builtin_amdgcn_sched_barrier(0);
    __builtin_amdgcn_s_barrier();   // all waves staged tile it
    __builtin_amdgcn_sched_barrier(0);

#pragma unroll
    for (int ks = 0; ks < 2; ks++) {
      const int chunk = (ks << 2) + kq;
      f16x8 af[2];
#pragma unroll
      for (int mf = 0; mf < 2; mf++)
        af[mf] = *(const f16x8*)((char*)As[cur] + swz(wrow + (mf << 4) + m_l, chunk));
#pragma unroll
      for (int kf = 0; kf < 4; kf++) {
        f16x8 bv = *(const f16x8*)((char*)Bs[cur] + swz((kf << 4) + m_l, chunk));
#pragma unroll
        for (int mf = 0; mf < 2; mf++)
          acc[mf][kf] = __builtin_amdgcn_mfma_f32_16x16x32_f16(
              af[mf], bv, acc[mf][kf], 0, 0, 0);
      }
    }
  }

#pragma unroll
  for (int kf = 0; kf < 4; kf++) {
    const int col = c0 + (kf << 4) + m_l;
    const float cb = Cb[col];
#pragma unroll
    for (int mf = 0; mf < 2; mf++) {
      const int rbase = r0 + wrow + (mf << 4) + (kq << 2);
#pragma unroll
      for (int r = 0; r < 4; r++)
        out[(size_t)(rbase + r) * ODIM + col] = acc[mf][kf][r] + cb;
    }
  }
}

// ---- launch --------------------------------------------------------------

extern "C" void kernel_launch(void* const* d_in, const int* in_sizes, int n_in,
                              void* d_out, int out_size, void* d_ws, size_t ws_size,
                              hipStream_t stream) {
  const float* z  = (const float*)d_in[0];
  const float* T0 = (const float*)d_in[1];
  const float* T  = (const float*)d_in[2];
  const float* Cw = (const float*)d_in[3];
  const float* Cb = (const float*)d_in[4];
  float* out = (float*)d_out;

  // ws layout: z16 64MB | Tb 2MB | Cwb 256KB | u8 32MB  (total ~98.25 MB)
  char* ws = (char*)d_ws;
  _Float16* z16 = (_Float16*)ws;
  _Float16* Tb  = (_Float16*)(ws + (size_t)ZN * 2);
  _Float16* Cwb = (_Float16*)(ws + (size_t)ZN * 2 + (size_t)TN * 2);
  _Float16* u8  = (_Float16*)(ws + (size_t)ZN * 2 + (size_t)TN * 2 + (size_t)CWN * 2);

  // (ZN+TN+CWN)/8 threads / 256 = 16960 blocks exactly
  k_convert<<<16960, 256, 0, stream>>>(z, T, Cw, z16, Tb, Cwb);
  k_poly<<<8192, 256, 0, stream>>>(z16, T0, Tb, u8);
  k_out<<<4096, 256, 0, stream>>>(u8, Cwb, Cb, out);
}

// Round 4
// 393.061 us; speedup vs baseline: 1.0031x; 1.0031x over previous
//
#include <hip/hip_runtime.h>
#include <hip/hip_fp16.h>
#include <cstdint>

// Problem constants (fixed by the reference)
#define NROWS 65536
#define DIM   512    // D
#define KDIM  256    // K
#define ODIM  512    // O
#define DEG   8
#define ZN    (NROWS * DIM)        // 33554432 z elements
#define TN    (DEG * KDIM * DIM)   // 1048576 T elements
#define CWN   (ODIM * KDIM)        // 131072 C_w elements

typedef _Float16 f16x8 __attribute__((ext_vector_type(8)));
typedef float    f32x4 __attribute__((ext_vector_type(4)));

// ---- helpers -------------------------------------------------------------

// async 16B global->LDS (global_load_lds_dwordx4). LDS dest is wave-uniform
// base + lane*16 by HW rule; all our slot mappings honor that.
__device__ __forceinline__ void gld_lds16(const void* g, void* l) {
  __builtin_amdgcn_global_load_lds(
      (const __attribute__((address_space(1))) unsigned int*)g,
      (__attribute__((address_space(3))) unsigned int*)l, 16, 0, 0);
}

__device__ __forceinline__ unsigned pack2h(float a, float b) {
  union { _Float16 h[2]; unsigned u; } x;
  x.h[0] = (_Float16)a; x.h[1] = (_Float16)b;
  return x.u;
}

// Swizzled byte offset in a tile of 64-half rows (128B = 8 x 16B chunks).
// chunk c of row r lives at slot (c+r)&7 -> conflict-free ds_read_b128.
__device__ __forceinline__ int swz(int row, int chunk) {
  return (row << 7) | (((chunk + row) & 7) << 4);
}

// ---- kernel 0: fp32->fp16 conversions (z, T with a_n folded, C_w) --------
// 8 elems/thread: 2x float4 in, 1x uint4 (16B) out — copy-shaped.

__global__ void k_convert(const float* __restrict__ z,
                          const float* __restrict__ T,
                          const float* __restrict__ Cw,
                          _Float16* __restrict__ z16,
                          _Float16* __restrict__ Tb,
                          _Float16* __restrict__ Cwb) {
  long e = ((long)blockIdx.x * 256 + threadIdx.x) * 8;
  const float* src;
  _Float16* dst;
  float s = 1.0f;
  if (e < ZN) {
    src = z + e; dst = z16 + e;
  } else {
    long o = e - ZN;
    if (o < TN) {
      int n = (int)(o >> 17);  // / (KDIM*DIM); Tb[n] holds degree n+1
      s = (n == 0) ? 1.0f : (float)(2 * n + 1) / (float)(n + 1);
      src = T + o; dst = Tb + o;
    } else {
      long c = o - TN;
      if (c >= CWN) return;
      src = Cw + c; dst = Cwb + c;
    }
  }
  float4 v0 = *(const float4*)src;
  float4 v1 = *(const float4*)(src + 4);
  uint4 p;
  p.x = pack2h(v0.x * s, v0.y * s); p.y = pack2h(v0.z * s, v0.w * s);
  p.z = pack2h(v1.x * s, v1.y * s); p.w = pack2h(v1.z * s, v1.w * s);
  *(uint4*)dst = p;
}

// ---- kernel 1: fused GEMM [Nx512]x[512x(16x8deg)] + degree recurrence ----
// LDS-BW analysis (r0/r2/r3 all pinned at 48.5% MfmaUtil = LDS-read ceiling):
// B-frag bytes/MFMA = 1024/mf. This version: 256-row blocks, 64 rows/wave
// (mf=4) -> 24 KB LDS-read per 64 MFMA per wave per iter = 375 B/MFMA vs
// 310 B/MFMA CU budget -> ceiling ~83% (was 640 B/MFMA -> 48.5%).
// Pipeline = round-2 proven template: A via gld_lds (issue-then-drain),
// B dbuf gld_lds at distance 1, counted vmcnt. Ledger at the wait in iter
// it (it<7): outstanding = B(it):4 + A(it):8 + B(it+1):4 = 16 -> vmcnt(4)
// drains A(it),B(it), leaves B(it+1) in flight across compute+barrier.
// XCD-pinned mapping: xcd=id&7 owns 32 consecutive row-tiles x all 16 kg ->
// z16 re-reads (16x) hit that XCD's L2; Tb (2MB) resident per-XCD.

__launch_bounds__(256, 2)
__global__ void k_poly(const _Float16* __restrict__ z16,
                       const float* __restrict__ T0,
                       const _Float16* __restrict__ Tb,
                       _Float16* __restrict__ u8) {
  __shared__ __align__(16) uint16_t As[256 * 64];      // 32 KB z tile
  __shared__ __align__(16) uint16_t Bs[2][128 * 64];   // 2 x 16 KB Tb tile

  const int tid = threadIdx.x;
  const int wave = tid >> 6, lane = tid & 63;

  // grid 4096 = 8 xcd * (32 rt * 16 kg)
  const int id = blockIdx.x;
  const int xcd = id & 7;
  const int s = id >> 3;                     // 0..511
  const int kg = s & 15;                     // 0..15 (16 u-cols each)
  const int rt = (xcd << 5) | (s >> 4);      // 0..255 row tile (256 rows)
  const int r0 = rt << 8;
  const int k0 = kg << 4;

  const int m_l = lane & 15, kq = lane >> 4;
  const int wrow = wave << 6;                // 64 rows per wave

  f32x4 acc[DEG][4];
#pragma unroll
  for (int n = 0; n < DEG; n++)
#pragma unroll
    for (int a = 0; a < 4; a++)
      acc[n][a] = (f32x4){0.f, 0.f, 0.f, 0.f};

  // Staging slots. lin=j*256+tid, row=lin>>3, c=((lin&7)-row)&7 inverts the
  // swizzle on the global side; LDS dest (lofs) is linear.
  const _Float16* aptr[8];
  int lofsA[8];
#pragma unroll
  for (int j = 0; j < 8; j++) {
    int lin = (j << 8) + tid;
    int row = lin >> 3;
    int c = ((lin & 7) - row) & 7;
    lofsA[j] = lin << 4;
    aptr[j] = z16 + (size_t)(r0 + row) * DIM + (c << 3);
  }
  const _Float16* bptr[4];
  int lofsB[4];
#pragma unroll
  for (int j = 0; j < 4; j++) {
    int lin = (j << 8) + tid;
    int row = lin >> 3;
    int c = ((lin & 7) - row) & 7;
    lofsB[j] = lin << 4;
    int n = row >> 4, kk = row & 15;
    bptr[j] = Tb + (size_t)((n << 8) + k0 + kk) * DIM + (c << 3);
  }

  // Prologue: issue B(0).
#pragma unroll
  for (int j = 0; j < 4; j++) gld_lds16(bptr[j], (char*)Bs[0] + lofsB[j]);
  __builtin_amdgcn_sched_barrier(0);

#pragma unroll
  for (int it = 0; it < DIM / 64; it++) {
    const int cur = it & 1;
    __builtin_amdgcn_s_barrier();   // readers of As & Bs[cur^1] done
    __builtin_amdgcn_sched_barrier(0);

    // issue A(it)
#pragma unroll
    for (int j = 0; j < 8; j++)
      gld_lds16(aptr[j] + (it << 6), (char*)As + lofsA[j]);
    __builtin_amdgcn_sched_barrier(0);

    // issue B(it+1), then counted wait
    if (it + 1 < DIM / 64) {
#pragma unroll
      for (int j = 0; j < 4; j++)
        gld_lds16(bptr[j] + ((it + 1) << 6), (char*)Bs[cur ^ 1] + lofsB[j]);
      __builtin_amdgcn_sched_barrier(0);
      asm volatile("s_waitcnt vmcnt(4)" ::: "memory");  // drain A(it),B(it)
    } else {
      asm volatile("s_waitcnt vmcnt(0)" ::: "memory");
    }
    __builtin_amdgcn_sched_barrier(0);
    __builtin_amdgcn_s_barrier();   // all waves' A(it),B(it) staged
    __builtin_amdgcn_sched_barrier(0);

    // compute tile it: 2 ks x 8 deg x 4 mf = 64 MFMA
#pragma unroll
    for (int ks = 0; ks < 2; ks++) {
      const int chunk = (ks << 2) + kq;
      f16x8 af[4];
#pragma unroll
      for (int mf = 0; mf < 4; mf++)
        af[mf] = *(const f16x8*)((char*)As + swz(wrow + (mf << 4) + m_l, chunk));
#pragma unroll
      for (int n = 0; n < DEG; n++) {
        f16x8 bv = *(const f16x8*)((char*)Bs[cur] + swz((n << 4) + m_l, chunk));
#pragma unroll
        for (int mf = 0; mf < 4; mf++)
          acc[n][mf] = __builtin_amdgcn_mfma_f32_16x16x32_f16(
              af[mf], bv, acc[n][mf], 0, 0, 0);
      }
    }
  }

  // Legendre recurrence per accumulator element, store u8 fp16.
  // C/D layout: col = lane&15, row = (lane>>4)*4 + reg  [m89-verified]
  const float bcoef[7] = {1.f/2.f, 2.f/3.f, 3.f/4.f, 4.f/5.f,
                          5.f/6.f, 6.f/7.f, 7.f/8.f};
  const int col = k0 + m_l;
  const float t0v = T0[col];
#pragma unroll
  for (int mf = 0; mf < 4; mf++) {
    f32x4 up2 = {t0v, t0v, t0v, t0v};
    f32x4 up1 = acc[0][mf];
#pragma unroll
    for (int n = 2; n <= DEG; n++) {
      f32x4 cur = acc[n - 1][mf] * up1 - bcoef[n - 2] * up2;
      up2 = up1; up1 = cur;
    }
    const int rbase = r0 + wrow + (mf << 4) + (kq << 2);
#pragma unroll
    for (int r = 0; r < 4; r++)
      u8[(size_t)(rbase + r) * KDIM + col] = (_Float16)up1[r];
  }
}

// ---- kernel 2: out[N,512] = u8[N,256] @ Cw^T + C_b (fp32 out) ------------
// Same LDS-BW surgery: 256 rows x 128 out-cols per block (mf=4, kf=8) ->
// 16 KB LDS-read per 64 MFMA per wave per iter -> ~83% ceiling (was 40%).
// Same pipeline template: A gld_lds issue-then-drain, B dbuf, vmcnt(4).
// XCD-pinned: 4 cg blocks of a row tile on one XCD -> u8 panel L2-shared.

__launch_bounds__(256, 2)
__global__ void k_out(const _Float16* __restrict__ u8,
                      const _Float16* __restrict__ Cwb,
                      const float* __restrict__ Cb,
                      float* __restrict__ out) {
  __shared__ __align__(16) uint16_t As[256 * 64];     // 32 KB u8 tile
  __shared__ __align__(16) uint16_t Bs[2][128 * 64];  // 2 x 16 KB Cw tile

  const int tid = threadIdx.x;
  const int wave = tid >> 6, lane = tid & 63;

  // grid 1024 = 8 xcd * (32 rt * 4 cg)
  const int id = blockIdx.x;
  const int xcd = id & 7;
  const int s = id >> 3;                     // 0..127
  const int cg = s & 3;                      // 0..3 out-col group (128)
  const int rt = (xcd << 5) | (s >> 2);      // 0..255 row tile (256 rows)
  const int r0 = rt << 8;
  const int c0 = cg << 7;

  const int m_l = lane & 15, kq = lane >> 4;
  const int wrow = wave << 6;                // 64 rows per wave

  f32x4 acc[4][8];
#pragma unroll
  for (int a = 0; a < 4; a++)
#pragma unroll
    for (int b = 0; b < 8; b++)
      acc[a][b] = (f32x4){0.f, 0.f, 0.f, 0.f};

  const _Float16* aptr[8];
  int lofsA[8];
#pragma unroll
  for (int j = 0; j < 8; j++) {
    int lin = (j << 8) + tid;
    int row = lin >> 3;
    int c = ((lin & 7) - row) & 7;
    lofsA[j] = lin << 4;
    aptr[j] = u8 + (size_t)(r0 + row) * KDIM + (c << 3);
  }
  const _Float16* bptr[4];
  int lofsB[4];
#pragma unroll
  for (int j = 0; j < 4; j++) {
    int lin = (j << 8) + tid;
    int row = lin >> 3;
    int c = ((lin & 7) - row) & 7;
    lofsB[j] = lin << 4;
    bptr[j] = Cwb + (size_t)(c0 + row) * KDIM + (c << 3);
  }

  // Prologue: issue B(0).
#pragma unroll
  for (int j = 0; j < 4; j++) gld_lds16(bptr[j], (char*)Bs[0] + lofsB[j]);
  __builtin_amdgcn_sched_barrier(0);

#pragma unroll
  for (int it = 0; it < KDIM / 64; it++) {
    const int cur = it & 1;
    __builtin_amdgcn_s_barrier();   // readers of As & Bs[cur^1] done
    __builtin_amdgcn_sched_barrier(0);

#pragma unroll
    for (int j = 0; j < 8; j++)
      gld_lds16(aptr[j] + (it << 6), (char*)As + lofsA[j]);
    __builtin_amdgcn_sched_barrier(0);

    if (it + 1 < KDIM / 64) {
#pragma unroll
      for (int j = 0; j < 4; j++)
        gld_lds16(bptr[j] + ((it + 1) << 6), (char*)Bs[cur ^ 1] + lofsB[j]);
      __builtin_amdgcn_sched_barrier(0);
      asm volatile("s_waitcnt vmcnt(4)" ::: "memory");  // drain A(it),B(it)
    } else {
      asm volatile("s_waitcnt vmcnt(0)" ::: "memory");
    }
    __builtin_amdgcn_sched_barrier(0);
    __builtin_amdgcn_s_barrier();
    __builtin_amdgcn_sched_barrier(0);

    // compute: 2 ks x 8 kf x 4 mf = 64 MFMA
#pragma unroll
    for (int ks = 0; ks < 2; ks++) {
      const int chunk = (ks << 2) + kq;
      f16x8 af[4];
#pragma unroll
      for (int mf = 0; mf < 4; mf++)
        af[mf] = *(const f16x8*)((char*)As + swz(wrow + (mf << 4) + m_l, chunk));
#pragma unroll
      for (int kf = 0; kf < 8; kf++) {
        f16x8 bv = *(const f16x8*)((char*)Bs[cur] + swz((kf << 4) + m_l, chunk));
#pragma unroll
        for (int mf = 0; mf < 4; mf++)
          acc[mf][kf] = __builtin_amdgcn_mfma_f32_16x16x32_f16(
              af[mf], bv, acc[mf][kf], 0, 0, 0);
      }
    }
  }

#pragma unroll
  for (int kf = 0; kf < 8; kf++) {
    const int col = c0 + (kf << 4) + m_l;
    const float cb = Cb[col];
#pragma unroll
    for (int mf = 0; mf < 4; mf++) {
      const int rbase = r0 + wrow + (mf << 4) + (kq << 2);
#pragma unroll
      for (int r = 0; r < 4; r++)
        out[(size_t)(rbase + r) * ODIM + col] = acc[mf][kf][r] + cb;
    }
  }
}

// ---- launch --------------------------------------------------------------

extern "C" void kernel_launch(void* const* d_in, const int* in_sizes, int n_in,
                              void* d_out, int out_size, void* d_ws, size_t ws_size,
                              hipStream_t stream) {
  const float* z  = (const float*)d_in[0];
  const float* T0 = (const float*)d_in[1];
  const float* T  = (const float*)d_in[2];
  const float* Cw = (const float*)d_in[3];
  const float* Cb = (const float*)d_in[4];
  float* out = (float*)d_out;

  // ws layout: z16 64MB | Tb 2MB | Cwb 256KB | u8 32MB  (total ~98.25 MB)
  char* ws = (char*)d_ws;
  _Float16* z16 = (_Float16*)ws;
  _Float16* Tb  = (_Float16*)(ws + (size_t)ZN * 2);
  _Float16* Cwb = (_Float16*)(ws + (size_t)ZN * 2 + (size_t)TN * 2);
  _Float16* u8  = (_Float16*)(ws + (size_t)ZN * 2 + (size_t)TN * 2 + (size_t)CWN * 2);

  // (ZN+TN+CWN)/8 threads / 256 = 16960 blocks exactly
  k_convert<<<16960, 256, 0, stream>>>(z, T, Cw, z16, Tb, Cwb);
  k_poly<<<4096, 256, 0, stream>>>(z16, T0, Tb, u8);
  k_out<<<1024, 256, 0, stream>>>(u8, Cwb, Cb, out);
}

// Round 6
// 392.421 us; speedup vs baseline: 1.0047x; 1.0016x over previous
//
#include <hip/hip_runtime.h>
#include <hip/hip_fp16.h>
#include <cstdint>

// Problem constants (fixed by the reference)
#define NROWS 65536
#define DIM   512    // D
#define KDIM  256    // K
#define ODIM  512    // O
#define DEG   8
#define ZN    (NROWS * DIM)        // 33554432 z elements
#define TN    (DEG * KDIM * DIM)   // 1048576 T elements
#define CWN   (ODIM * KDIM)        // 131072 C_w elements

typedef _Float16 f16x8 __attribute__((ext_vector_type(8)));
typedef float    f32x4 __attribute__((ext_vector_type(4)));

// ---- helpers -------------------------------------------------------------

// async 16B global->LDS (global_load_lds_dwordx4). LDS dest is wave-uniform
// base + lane*16 by HW rule; all our slot mappings honor that.
__device__ __forceinline__ void gld_lds16(const void* g, void* l) {
  __builtin_amdgcn_global_load_lds(
      (const __attribute__((address_space(1))) unsigned int*)g,
      (__attribute__((address_space(3))) unsigned int*)l, 16, 0, 0);
}

__device__ __forceinline__ unsigned pack2h(float a, float b) {
  union { _Float16 h[2]; unsigned u; } x;
  x.h[0] = (_Float16)a; x.h[1] = (_Float16)b;
  return x.u;
}

// K64 tile swizzle (k_out): 64-half rows (128B = 8 x 16B chunks),
// chunk c of row r at slot (c+r)&7 -> conflict-free ds_read_b128.
__device__ __forceinline__ int swz(int row, int chunk) {
  return (row << 7) | (((chunk + row) & 7) << 4);
}

// K32 tile swizzle (k_poly): 32-half rows (64B = 4 x 16B chunks).
// slot(r,c) = (c + r + (r>>2)) & 3. For a 16-lane quarter-wave reading
// fixed chunk over rows i=0..15: slot-class (4i + slot) mod 8 spreads
// 16 lanes over 8 classes 2-way -> conflict-free (2-way is free, m136).
__device__ __forceinline__ int swz32(int row, int chunk) {
  return (row << 6) | (((chunk + row + (row >> 2)) & 3) << 4);
}

// ---- kernel 0: fp32->fp16 conversions (z, T with a_n folded, C_w) --------
// 8 elems/thread: 2x float4 in, 1x uint4 (16B) out — copy-shaped.

__global__ void k_convert(const float* __restrict__ z,
                          const float* __restrict__ T,
                          const float* __restrict__ Cw,
                          _Float16* __restrict__ z16,
                          _Float16* __restrict__ Tb,
                          _Float16* __restrict__ Cwb) {
  long e = ((long)blockIdx.x * 256 + threadIdx.x) * 8;
  const float* src;
  _Float16* dst;
  float s = 1.0f;
  if (e < ZN) {
    src = z + e; dst = z16 + e;
  } else {
    long o = e - ZN;
    if (o < TN) {
      int n = (int)(o >> 17);  // / (KDIM*DIM); Tb[n] holds degree n+1
      s = (n == 0) ? 1.0f : (float)(2 * n + 1) / (float)(n + 1);
      src = T + o; dst = Tb + o;
    } else {
      long c = o - TN;
      if (c >= CWN) return;
      src = Cw + c; dst = Cwb + c;
    }
  }
  float4 v0 = *(const float4*)src;
  float4 v1 = *(const float4*)(src + 4);
  uint4 p;
  p.x = pack2h(v0.x * s, v0.y * s); p.y = pack2h(v0.z * s, v0.w * s);
  p.z = pack2h(v1.x * s, v1.y * s); p.w = pack2h(v1.z * s, v1.w * s);
  *(uint4*)dst = p;
}

// ---- kernel 1: fused GEMM [Nx512]x[512x(16x8deg)] + degree recurrence ----
// Rounds 0-4 all pinned at ~50% MfmaUtil: A was issued-then-drained inside
// one barrier interval every iteration (exposed L2 latency). Fix: K-step 32
// so BOTH operands double-buffer in 48 KB (static cap is 64 KB):
//   As 2 x (256 rows x 32 halves) = 32 KB, Bs 2 x (128 x 32) = 16 KB.
// Per iter: barrier; issue A(it+1):4 + B(it+1):2; vmcnt(6) — queue is
// A(it):4+B(it):2+A(it+1):4+B(it+1):2 = 12, so vmcnt(6) drains exactly
// A(it),B(it), both issued one FULL iteration earlier; barrier; 32 MFMA.
// Nothing is issue-then-drained. mf=4 (64 rows/wave) keeps B-read
// amortization. 2 blocks/CU (reg-bound: 128 acc AGPR + ~80 VGPR).
// T5 setprio around MFMA cluster (stage/compute role-split exists now).
// XCD-pinned: xcd=id&7 owns 32 row-tiles x 16 kg -> z16 re-reads L2-local.

__launch_bounds__(256, 2)
__global__ void k_poly(const _Float16* __restrict__ z16,
                       const float* __restrict__ T0,
                       const _Float16* __restrict__ Tb,
                       _Float16* __restrict__ u8) {
  __shared__ __align__(16) uint16_t As[2][256 * 32];   // 2 x 16 KB z tile
  __shared__ __align__(16) uint16_t Bs[2][128 * 32];   // 2 x  8 KB Tb tile

  const int tid = threadIdx.x;
  const int wave = tid >> 6, lane = tid & 63;

  // grid 4096 = 8 xcd * (32 rt * 16 kg)
  const int id = blockIdx.x;
  const int xcd = id & 7;
  const int s = id >> 3;                     // 0..511
  const int kg = s & 15;                     // 0..15 (16 u-cols each)
  const int rt = (xcd << 5) | (s >> 4);      // 0..255 row tile (256 rows)
  const int r0 = rt << 8;
  const int k0 = kg << 4;

  const int m_l = lane & 15, kq = lane >> 4;
  const int wrow = wave << 6;                // 64 rows per wave

  f32x4 acc[DEG][4];
#pragma unroll
  for (int n = 0; n < DEG; n++)
#pragma unroll
    for (int a = 0; a < 4; a++)
      acc[n][a] = (f32x4){0.f, 0.f, 0.f, 0.f};

  // A staging: 4 slots/thread. lin=j*256+tid in [0,1024), row=lin>>2,
  // sl=lin&3, source chunk c=(sl-row-(row>>2))&3 inverts swz32.
  const _Float16* aptr[4];
  int lofsA[4];
#pragma unroll
  for (int j = 0; j < 4; j++) {
    int lin = (j << 8) + tid;
    int row = lin >> 2;
    int c = ((lin & 3) - row - (row >> 2)) & 3;
    lofsA[j] = lin << 4;
    aptr[j] = z16 + (size_t)(r0 + row) * DIM + (c << 3);
  }
  // B staging: 2 slots/thread. lin in [0,512), row=lin>>2 in [0,128).
  const _Float16* bptr[2];
  int lofsB[2];
#pragma unroll
  for (int j = 0; j < 2; j++) {
    int lin = (j << 8) + tid;
    int row = lin >> 2;
    int c = ((lin & 3) - row - (row >> 2)) & 3;
    lofsB[j] = lin << 4;
    int n = row >> 4, kk = row & 15;
    bptr[j] = Tb + (size_t)((n << 8) + k0 + kk) * DIM + (c << 3);
  }

  // Prologue: issue A(0), B(0).
#pragma unroll
  for (int j = 0; j < 4; j++) gld_lds16(aptr[j], (char*)As[0] + lofsA[j]);
#pragma unroll
  for (int j = 0; j < 2; j++) gld_lds16(bptr[j], (char*)Bs[0] + lofsB[j]);
  __builtin_amdgcn_sched_barrier(0);

#pragma unroll
  for (int it = 0; it < DIM / 32; it++) {
    const int cur = it & 1;
    __builtin_amdgcn_s_barrier();   // readers of [cur^1] buffers done
    __builtin_amdgcn_sched_barrier(0);

    if (it + 1 < DIM / 32) {
#pragma unroll
      for (int j = 0; j < 4; j++)
        gld_lds16(aptr[j] + ((it + 1) << 5), (char*)As[cur ^ 1] + lofsA[j]);
#pragma unroll
      for (int j = 0; j < 2; j++)
        gld_lds16(bptr[j] + ((it + 1) << 5), (char*)Bs[cur ^ 1] + lofsB[j]);
      __builtin_amdgcn_sched_barrier(0);
      asm volatile("s_waitcnt vmcnt(6)" ::: "memory");  // drain A(it),B(it)
    } else {
      asm volatile("s_waitcnt vmcnt(0)" ::: "memory");
    }
    __builtin_amdgcn_sched_barrier(0);
    __builtin_amdgcn_s_barrier();   // all waves' tile-it loads landed
    __builtin_amdgcn_sched_barrier(0);

    // compute tile it: 8 deg x 4 mf = 32 MFMA (K=32, chunk = kq)
    f16x8 af[4];
#pragma unroll
    for (int mf = 0; mf < 4; mf++)
      af[mf] = *(const f16x8*)((char*)As[cur] +
                               swz32(wrow + (mf << 4) + m_l, kq));
    __builtin_amdgcn_s_setprio(1);
#pragma unroll
    for (int n = 0; n < DEG; n++) {
      f16x8 bv = *(const f16x8*)((char*)Bs[cur] + swz32((n << 4) + m_l, kq));
#pragma unroll
      for (int mf = 0; mf < 4; mf++)
        acc[n][mf] = __builtin_amdgcn_mfma_f32_16x16x32_f16(
            af[mf], bv, acc[n][mf], 0, 0, 0);
    }
    __builtin_amdgcn_s_setprio(0);
  }

  // Legendre recurrence per accumulator element, store u8 fp16.
  // C/D layout: col = lane&15, row = (lane>>4)*4 + reg  [m89-verified]
  const float bcoef[7] = {1.f/2.f, 2.f/3.f, 3.f/4.f, 4.f/5.f,
                          5.f/6.f, 6.f/7.f, 7.f/8.f};
  const int col = k0 + m_l;
  const float t0v = T0[col];
#pragma unroll
  for (int mf = 0; mf < 4; mf++) {
    f32x4 up2 = {t0v, t0v, t0v, t0v};
    f32x4 up1 = acc[0][mf];
#pragma unroll
    for (int n = 2; n <= DEG; n++) {
      f32x4 cur = acc[n - 1][mf] * up1 - bcoef[n - 2] * up2;
      up2 = up1; up1 = cur;
    }
    const int rbase = r0 + wrow + (mf << 4) + (kq << 2);
#pragma unroll
    for (int r = 0; r < 4; r++)
      u8[(size_t)(rbase + r) * KDIM + col] = (_Float16)up1[r];
  }
}

// ---- kernel 2: out[N,512] = u8[N,256] @ Cw^T + C_b (fp32 out) ------------
// EXACT round-3 version (best measured k_out by cross-round subtraction;
// round-4's 256x128 tile regressed ~26 us). 128 rows x 64 out-cols,
// both As/Bs double-buffered, counted vmcnt(6), 48 KB, 3 blocks/CU.
// XCD swizzle: 8 cg blocks of a row tile share u8 rows -> same XCD L2.

__launch_bounds__(256, 3)
__global__ void k_out(const _Float16* __restrict__ u8,
                      const _Float16* __restrict__ Cwb,
                      const float* __restrict__ Cb,
                      float* __restrict__ out) {
  __shared__ __align__(16) uint16_t As[2][128 * 64];  // 2 x 16 KB u8 tile
  __shared__ __align__(16) uint16_t Bs[2][64 * 64];   // 2 x  8 KB Cw tile

  const int tid = threadIdx.x;
  const int wave = tid >> 6, lane = tid & 63;

  const int id = blockIdx.x;
  const int xcd = id & 7;
  const int s = id >> 3;                     // 0..511
  const int cg = s & 7;                      // 0..7 out-col group (64)
  const int rt = (xcd << 6) | (s >> 3);      // 0..511 row tile
  const int r0 = rt << 7;
  const int c0 = cg << 6;

  const int m_l = lane & 15, kq = lane >> 4;
  const int wrow = wave << 5;

  f32x4 acc[2][4];
#pragma unroll
  for (int a = 0; a < 2; a++)
#pragma unroll
    for (int b = 0; b < 4; b++)
      acc[a][b] = (f32x4){0.f, 0.f, 0.f, 0.f};

  const _Float16* aptr[4];
  const _Float16* bptr[2];
  int lofsA[4], lofsB[2];
#pragma unroll
  for (int j = 0; j < 4; j++) {
    int lin = (j << 8) + tid;
    int row = lin >> 3;
    int c = ((lin & 7) - row) & 7;
    lofsA[j] = lin << 4;
    aptr[j] = u8 + (size_t)(r0 + row) * KDIM + (c << 3);
  }
#pragma unroll
  for (int j = 0; j < 2; j++) {
    int lin = (j << 8) + tid;
    int row = lin >> 3;
    int c = ((lin & 7) - row) & 7;
    lofsB[j] = lin << 4;
    bptr[j] = Cwb + (size_t)(c0 + row) * KDIM + (c << 3);
  }

  // Prologue: issue A(0) then B(0) (order pinned; ledger depends on it).
#pragma unroll
  for (int j = 0; j < 4; j++) gld_lds16(aptr[j], (char*)As[0] + lofsA[j]);
  __builtin_amdgcn_sched_barrier(0);
#pragma unroll
  for (int j = 0; j < 2; j++) gld_lds16(bptr[j], (char*)Bs[0] + lofsB[j]);
  __builtin_amdgcn_sched_barrier(0);

#pragma unroll
  for (int it = 0; it < KDIM / 64; it++) {
    const int cur = it & 1;
    __builtin_amdgcn_s_barrier();   // readers of [cur^1] buffers done
    __builtin_amdgcn_sched_barrier(0);

    if (it + 1 < KDIM / 64) {
#pragma unroll
      for (int j = 0; j < 4; j++)
        gld_lds16(aptr[j] + ((it + 1) << 6), (char*)As[cur ^ 1] + lofsA[j]);
      __builtin_amdgcn_sched_barrier(0);
#pragma unroll
      for (int j = 0; j < 2; j++)
        gld_lds16(bptr[j] + ((it + 1) << 6), (char*)Bs[cur ^ 1] + lofsB[j]);
      __builtin_amdgcn_sched_barrier(0);
      asm volatile("s_waitcnt vmcnt(6)" ::: "memory");  // drain A(it),B(it)
    } else {
      asm volatile("s_waitcnt vmcnt(0)" ::: "memory");
    }
    __builtin_amdgcn_sched_barrier(0);
    __builtin_amdgcn_s_barrier();   // all waves staged tile it
    __builtin_amdgcn_sched_barrier(0);

#pragma unroll
    for (int ks = 0; ks < 2; ks++) {
      const int chunk = (ks << 2) + kq;
      f16x8 af[2];
#pragma unroll
      for (int mf = 0; mf < 2; mf++)
        af[mf] = *(const f16x8*)((char*)As[cur] + swz(wrow + (mf << 4) + m_l, chunk));
#pragma unroll
      for (int kf = 0; kf < 4; kf++) {
        f16x8 bv = *(const f16x8*)((char*)Bs[cur] + swz((kf << 4) + m_l, chunk));
#pragma unroll
        for (int mf = 0; mf < 2; mf++)
          acc[mf][kf] = __builtin_amdgcn_mfma_f32_16x16x32_f16(
              af[mf], bv, acc[mf][kf], 0, 0, 0);
      }
    }
  }

#pragma unroll
  for (int kf = 0; kf < 4; kf++) {
    const int col = c0 + (kf << 4) + m_l;
    const float cb = Cb[col];
#pragma unroll
    for (int mf = 0; mf < 2; mf++) {
      const int rbase = r0 + wrow + (mf << 4) + (kq << 2);
#pragma unroll
      for (int r = 0; r < 4; r++)
        out[(size_t)(rbase + r) * ODIM + col] = acc[mf][kf][r] + cb;
    }
  }
}

// ---- launch --------------------------------------------------------------

extern "C" void kernel_launch(void* const* d_in, const int* in_sizes, int n_in,
                              void* d_out, int out_size, void* d_ws, size_t ws_size,
                              hipStream_t stream) {
  const float* z  = (const float*)d_in[0];
  const float* T0 = (const float*)d_in[1];
  const float* T  = (const float*)d_in[2];
  const float* Cw = (const float*)d_in[3];
  const float* Cb = (const float*)d_in[4];
  float* out = (float*)d_out;

  // ws layout: z16 64MB | Tb 2MB | Cwb 256KB | u8 32MB  (total ~98.25 MB)
  char* ws = (char*)d_ws;
  _Float16* z16 = (_Float16*)ws;
  _Float16* Tb  = (_Float16*)(ws + (size_t)ZN * 2);
  _Float16* Cwb = (_Float16*)(ws + (size_t)ZN * 2 + (size_t)TN * 2);
  _Float16* u8  = (_Float16*)(ws + (size_t)ZN * 2 + (size_t)TN * 2 + (size_t)CWN * 2);

  // (ZN+TN+CWN)/8 threads / 256 = 16960 blocks exactly
  k_convert<<<16960, 256, 0, stream>>>(z, T, Cw, z16, Tb, Cwb);
  k_poly<<<4096, 256, 0, stream>>>(z16, T0, Tb, u8);
  k_out<<<4096, 256, 0, stream>>>(u8, Cwb, Cb, out);
}